// Round 9
// baseline (524.413 us; speedup 1.0000x reference)
//
#include <hip/hip_runtime.h>

#define NG 8   // graphs

typedef _Float16 half8 __attribute__((ext_vector_type(8)));
typedef float    f32x4 __attribute__((ext_vector_type(4)));

// ---------------- casts ----------------

__global__ __launch_bounds__(256)
void k_cast16(const float* __restrict__ in, _Float16* __restrict__ out, int n8) {
    int i = blockIdx.x * 256 + threadIdx.x;
    if (i < n8) {
        const float4 a = *(const float4*)(in + (size_t)i * 8);
        const float4 b = *(const float4*)(in + (size_t)i * 8 + 4);
        half8 o;
        o[0] = (_Float16)a.x; o[1] = (_Float16)a.y; o[2] = (_Float16)a.z; o[3] = (_Float16)a.w;
        o[4] = (_Float16)b.x; o[5] = (_Float16)b.y; o[6] = (_Float16)b.z; o[7] = (_Float16)b.w;
        *(half8*)(out + (size_t)i * 8) = o;
    }
}

// ---------------- CSR build ----------------

__global__ __launch_bounds__(256)
void k_deg(const int* __restrict__ dst, int* __restrict__ deg, int E) {
    int i = blockIdx.x * 256 + threadIdx.x;
    if (i < E) atomicAdd(&deg[dst[i]], 1);
}

__global__ __launch_bounds__(1024)
void k_scan_a(const int* __restrict__ deg, int* __restrict__ incl,
              int* __restrict__ bsum, int n) {
    __shared__ int s[1024];
    int t = threadIdx.x;
    int base = blockIdx.x * 1024;
    int v = (base + t < n) ? deg[base + t] : 0;
    s[t] = v;
    __syncthreads();
    for (int off = 1; off < 1024; off <<= 1) {
        int x = 0;
        if (t >= off) x = s[t - off];
        __syncthreads();
        if (t >= off) s[t] += x;
        __syncthreads();
    }
    if (base + t < n) incl[base + t] = s[t];
    if (t == 1023) bsum[blockIdx.x] = s[1023];
}

__global__ void k_scan_b(int* bsum, int nb) {
    if (threadIdx.x == 0 && blockIdx.x == 0) {
        int run = 0;
        for (int i = 0; i < nb; ++i) { int v = bsum[i]; bsum[i] = run; run += v; }
    }
}

__global__ __launch_bounds__(256)
void k_scan_c(const int* __restrict__ incl, const int* __restrict__ deg,
              const int* __restrict__ bsum, int* __restrict__ rowp, int n) {
    int i = blockIdx.x * 256 + threadIdx.x;
    if (i < n) rowp[i] = incl[i] - deg[i] + bsum[i >> 10];
}

__global__ __launch_bounds__(256)
void k_scatter(const int* __restrict__ src, const int* __restrict__ dst,
               const int* __restrict__ rowp, int* __restrict__ cur,
               int* __restrict__ ss, int E) {
    int i = blockIdx.x * 256 + threadIdx.x;
    if (i < E) {
        int d = dst[i];
        int pos = rowp[d] + atomicAdd(&cur[d], 1);
        ss[pos] = src[i];
    }
}

// ---------------- aggregation (fp16 rows, fp32 accum), fused BN-apply+ReLU ----------------

template<int K, bool AFFINE>
__global__ __launch_bounds__(256)
void k_agg16(const _Float16* __restrict__ h, const int* __restrict__ rowp,
             const int* __restrict__ deg, const int* __restrict__ ss,
             const float* __restrict__ eps, const float* __restrict__ scp,
             const float* __restrict__ shp, _Float16* __restrict__ z, int n) {
    constexpr int TPN = K / 8;
    constexpr int NPB = 256 / TPN;
    int node = blockIdx.x * NPB + threadIdx.x / TPN;
    int lane = threadIdx.x % TPN;
    if (node >= n) return;
    float e1 = 1.0f + eps[0];
    const int c0 = lane * 8;
    float sc[8], sh[8];
    if (AFFINE) {
#pragma unroll
        for (int e = 0; e < 8; ++e) { sc[e] = scp[c0 + e]; sh[e] = shp[c0 + e]; }
    }
    size_t base = (size_t)node * K + c0;
    half8 v = *(const half8*)(h + base);
    float a[8];
#pragma unroll
    for (int e = 0; e < 8; ++e) {
        float f = (float)v[e];
        if (AFFINE) f = fmaxf(f * sc[e] + sh[e], 0.0f);
        a[e] = f * e1;
    }
    int s  = rowp[node];
    int dn = deg[node];
    int j = 0;
    for (; j + 4 <= dn; j += 4) {
        int u0 = ss[s + j], u1 = ss[s + j + 1], u2 = ss[s + j + 2], u3 = ss[s + j + 3];
        half8 h0 = *(const half8*)(h + (size_t)u0 * K + c0);
        half8 h1 = *(const half8*)(h + (size_t)u1 * K + c0);
        half8 h2 = *(const half8*)(h + (size_t)u2 * K + c0);
        half8 h3 = *(const half8*)(h + (size_t)u3 * K + c0);
#pragma unroll
        for (int e = 0; e < 8; ++e) {
            float f0 = (float)h0[e], f1 = (float)h1[e];
            float f2 = (float)h2[e], f3 = (float)h3[e];
            if (AFFINE) {
                f0 = fmaxf(f0 * sc[e] + sh[e], 0.0f);
                f1 = fmaxf(f1 * sc[e] + sh[e], 0.0f);
                f2 = fmaxf(f2 * sc[e] + sh[e], 0.0f);
                f3 = fmaxf(f3 * sc[e] + sh[e], 0.0f);
            }
            a[e] += (f0 + f1) + (f2 + f3);
        }
    }
    for (; j < dn; ++j) {
        int u = ss[s + j];
        half8 hv = *(const half8*)(h + (size_t)u * K + c0);
#pragma unroll
        for (int e = 0; e < 8; ++e) {
            float f = (float)hv[e];
            if (AFFINE) f = fmaxf(f * sc[e] + sh[e], 0.0f);
            a[e] += f;
        }
    }
    half8 o;
#pragma unroll
    for (int e = 0; e < 8; ++e) o[e] = (_Float16)a[e];
    *(half8*)(z + base) = o;
}

// ---------------- fused MLP: C = (A@W1^T+b1).relu() @ W2^T + b2, + BN partials ----------------
// A: [n x K] fp16; W1: [MID x K] fp16; W2: [MOUT x MID] fp16.
// One block = 64 rows, 512 threads (8 waves, 2 row-halves x 4 col-quarters).
// Y (64 x MID) lives in LDS between the two GEMMs. No global atomics:
// per-(block, row-half) BN partials at partial[(bid*2+wr)*2*MOUT + {c, MOUT+c}].

template<int K, int MID, int MOUT>
__global__ __launch_bounds__(512)
void k_mlp(const _Float16* __restrict__ A, const _Float16* __restrict__ W1,
           const float* __restrict__ b1, const _Float16* __restrict__ W2,
           const float* __restrict__ b2, _Float16* __restrict__ C,
           float* __restrict__ partial, int n) {
    constexpr int FN1 = MID / 64, WC1 = 16 * FN1;
    constexpr int FN2 = MOUT / 64, WC2 = 16 * FN2;
    constexpr int BI1 = MID / 64;    // W1 staging issues per k-step
    constexpr int BI2 = MOUT / 64;   // W2 staging issues per k-step
    __shared__ char smem[8192 + 32768 + MID * 128];
    char* As = smem;                 // [64][128B]
    char* Ws = smem + 8192;          // [max rows][128B] (W1, then W2)
    char* Ys = smem + 8192 + 32768;  // [64][MID*2 B], XOR-swizzled
    const int tid  = threadIdx.x;
    const int lane = tid & 63;
    const int wid  = tid >> 6;
    const int wr   = wid >> 2;       // 0..1
    const int wc   = wid & 3;        // 0..3
    const int brow = blockIdx.x * 64;
    const int srow = tid >> 3;       // 0..63
    const int spk  = (tid & 7) << 4; // 0..112
    const int lkA  = spk ^ ((srow & 7) << 4);

    // ================= phase 1: Y = relu(A @ W1^T + b1) =================
    f32x4 acc1[2][FN1];
#pragma unroll
    for (int m = 0; m < 2; ++m)
#pragma unroll
        for (int nn = 0; nn < FN1; ++nn) acc1[m][nn] = (f32x4){0.f, 0.f, 0.f, 0.f};

    uint4 ar, wr1[BI1];
    const int nk1 = K >> 6;
    {
        int ga = brow + srow; if (ga > n - 1) ga = n - 1;
        ar = *(const uint4*)((const char*)A + ((size_t)ga * K) * 2 + lkA);
#pragma unroll
        for (int i = 0; i < BI1; ++i)
            wr1[i] = *(const uint4*)((const char*)W1 + ((size_t)(i * 64 + srow) * K) * 2 + lkA);
    }
    for (int t = 0; t < nk1; ++t) {
        __syncthreads();
        *(uint4*)(As + srow * 128 + spk) = ar;
#pragma unroll
        for (int i = 0; i < BI1; ++i)
            *(uint4*)(Ws + (i * 64 + srow) * 128 + spk) = wr1[i];
        __syncthreads();
        if (t + 1 < nk1) {
            int k0 = (t + 1) << 6;
            int ga = brow + srow; if (ga > n - 1) ga = n - 1;
            ar = *(const uint4*)((const char*)A + ((size_t)ga * K + k0) * 2 + lkA);
#pragma unroll
            for (int i = 0; i < BI1; ++i)
                wr1[i] = *(const uint4*)((const char*)W1 + ((size_t)(i * 64 + srow) * K + k0) * 2 + lkA);
        }
#pragma unroll
        for (int kk = 0; kk < 2; ++kk) {
            const int kb = kk * 64 + (lane >> 4) * 16;
            half8 af[2], bf[FN1];
#pragma unroll
            for (int m = 0; m < 2; ++m) {
                int rowA = wr * 32 + m * 16 + (lane & 15);
                af[m] = *(const half8*)(As + rowA * 128 + (kb ^ ((rowA & 7) << 4)));
            }
#pragma unroll
            for (int nn = 0; nn < FN1; ++nn) {
                int rowB = wc * WC1 + nn * 16 + (lane & 15);
                bf[nn] = *(const half8*)(Ws + rowB * 128 + (kb ^ ((rowB & 7) << 4)));
            }
#pragma unroll
            for (int m = 0; m < 2; ++m)
#pragma unroll
                for (int nn = 0; nn < FN1; ++nn)
                    acc1[m][nn] = __builtin_amdgcn_mfma_f32_16x16x32_f16(af[m], bf[nn], acc1[m][nn], 0, 0, 0);
        }
    }

    // bias + relu -> Ys (fp16, swizzled)
    {
        float bb1[FN1];
#pragma unroll
        for (int nn = 0; nn < FN1; ++nn) bb1[nn] = b1[wc * WC1 + nn * 16 + (lane & 15)];
#pragma unroll
        for (int m = 0; m < 2; ++m)
#pragma unroll
            for (int nn = 0; nn < FN1; ++nn)
#pragma unroll
                for (int j = 0; j < 4; ++j) {
                    int row = wr * 32 + m * 16 + (lane >> 4) * 4 + j;
                    int col = wc * WC1 + nn * 16 + (lane & 15);
                    float v = fmaxf(acc1[m][nn][j] + bb1[nn], 0.0f);
                    *(_Float16*)(Ys + row * (MID * 2) + ((col * 2) ^ ((row & 7) << 4))) = (_Float16)v;
                }
    }

    // ================= phase 2: C = Y @ W2^T + b2 =================
    f32x4 acc2[2][FN2];
#pragma unroll
    for (int m = 0; m < 2; ++m)
#pragma unroll
        for (int nn = 0; nn < FN2; ++nn) acc2[m][nn] = (f32x4){0.f, 0.f, 0.f, 0.f};

    uint4 wr2[BI2];
#pragma unroll
    for (int i = 0; i < BI2; ++i)
        wr2[i] = *(const uint4*)((const char*)W2 + ((size_t)(i * 64 + srow) * MID) * 2 + lkA);

    const int nk2 = MID >> 6;
    for (int t = 0; t < nk2; ++t) {
        __syncthreads();   // t=0: Y visible + W1 reads done; t>0: prior W2 reads done
#pragma unroll
        for (int i = 0; i < BI2; ++i)
            *(uint4*)(Ws + (i * 64 + srow) * 128 + spk) = wr2[i];
        __syncthreads();
        if (t + 1 < nk2) {
            int k0 = (t + 1) << 6;
#pragma unroll
            for (int i = 0; i < BI2; ++i)
                wr2[i] = *(const uint4*)((const char*)W2 + ((size_t)(i * 64 + srow) * MID + k0) * 2 + lkA);
        }
#pragma unroll
        for (int kk = 0; kk < 2; ++kk) {
            const int kb = kk * 64 + (lane >> 4) * 16;
            half8 af[2], bf[FN2];
#pragma unroll
            for (int m = 0; m < 2; ++m) {
                int rowA = wr * 32 + m * 16 + (lane & 15);
                af[m] = *(const half8*)(Ys + rowA * (MID * 2) + ((t * 128 + kb) ^ ((rowA & 7) << 4)));
            }
#pragma unroll
            for (int nn = 0; nn < FN2; ++nn) {
                int rowB = wc * WC2 + nn * 16 + (lane & 15);
                bf[nn] = *(const half8*)(Ws + rowB * 128 + (kb ^ ((rowB & 7) << 4)));
            }
#pragma unroll
            for (int m = 0; m < 2; ++m)
#pragma unroll
                for (int nn = 0; nn < FN2; ++nn)
                    acc2[m][nn] = __builtin_amdgcn_mfma_f32_16x16x32_f16(af[m], bf[nn], acc2[m][nn], 0, 0, 0);
        }
    }

    // ================= epilogue: coalesced store + BN partials =================
    __syncthreads();   // Ws/As reads done; reuse smem as transpose buffers
    char* tb = smem + wid * 2304;   // per-wave [16][72] fp16 (144 B row stride)
    const int colbase = wc * WC2;
    float bb2[FN2];
#pragma unroll
    for (int nn = 0; nn < FN2; ++nn) bb2[nn] = b2[colbase + nn * 16 + (lane & 15)];
    constexpr int GRP = FN2 * 2;
    constexpr int RPI = 64 / GRP;
    constexpr int NIT = 16 / RPI;
    const int g    = lane & (GRP - 1);
    const int rl   = lane / GRP;
    const int rcol = colbase + g * 8;
    const int rowbase = brow + wr * 32;
    float s[8], q[8];
#pragma unroll
    for (int e = 0; e < 8; ++e) { s[e] = 0.f; q[e] = 0.f; }
#pragma unroll
    for (int m = 0; m < 2; ++m) {
#pragma unroll
        for (int nn = 0; nn < FN2; ++nn)
#pragma unroll
            for (int j = 0; j < 4; ++j) {
                float v = acc2[m][nn][j] + bb2[nn];
                *(_Float16*)(tb + ((lane >> 4) * 4 + j) * 144 + (nn * 16 + (lane & 15)) * 2) = (_Float16)v;
            }
#pragma unroll
        for (int it = 0; it < NIT; ++it) {
            int lr = it * RPI + rl;
            int grow = rowbase + m * 16 + lr;
            half8 v = *(const half8*)(tb + lr * 144 + g * 16);
            if (grow < n) {
                *(half8*)(C + (size_t)grow * MOUT + rcol) = v;
#pragma unroll
                for (int e = 0; e < 8; ++e) { float f = (float)v[e]; s[e] += f; q[e] += f * f; }
            }
        }
    }
#pragma unroll
    for (int e = 0; e < 8; ++e) {
        for (int mk = GRP; mk < 64; mk <<= 1) {
            s[e] += __shfl_xor(s[e], mk, 64);
            q[e] += __shfl_xor(q[e], mk, 64);
        }
    }
    if (lane < GRP) {
        float* p = partial + ((size_t)blockIdx.x * 2 + wr) * 2 * MOUT;
#pragma unroll
        for (int e = 0; e < 8; ++e) {
            p[rcol + e]        = s[e];
            p[MOUT + rcol + e] = q[e];
        }
    }
}

// ---------------- BN reduce: partial rows -> scale/shift ----------------
// grid = M/4 blocks x 256 threads (1 wave per column).

template<int M>
__global__ __launch_bounds__(256)
void k_bnred(const float* __restrict__ partial, const float* __restrict__ gamma,
             const float* __restrict__ beta, float* __restrict__ scale,
             float* __restrict__ shift, int n, int nrows) {
    const int w = threadIdx.x >> 6, lane = threadIdx.x & 63;
    const int c = blockIdx.x * 4 + w;
    float s = 0.f, q = 0.f;
    for (int b = lane; b < nrows; b += 64) {
        s += partial[(size_t)b * 2 * M + c];
        q += partial[(size_t)b * 2 * M + M + c];
    }
#pragma unroll
    for (int mk = 1; mk < 64; mk <<= 1) {
        s += __shfl_xor(s, mk, 64);
        q += __shfl_xor(q, mk, 64);
    }
    if (lane == 0) {
        float invN = 1.0f / (float)n;
        float mean = s * invN;
        float var  = q * invN - mean * mean;
        float sc   = rsqrtf(var + 1e-5f) * gamma[c];
        scale[c] = sc;
        shift[c] = beta[c] - mean * sc;
    }
}

// ---------------- graph readout (fused final BN affine) ----------------

__global__ __launch_bounds__(256)
void k_readout_bn(const _Float16* __restrict__ z, const float* __restrict__ scale,
                  const float* __restrict__ shift, const int* __restrict__ gid,
                  float* __restrict__ gsum, int* __restrict__ gcnt, int n) {
    __shared__ float ls[NG * 128];
    __shared__ int   lc[NG];
    for (int i = threadIdx.x; i < NG * 128; i += 256) ls[i] = 0.0f;
    if (threadIdx.x < NG) lc[threadIdx.x] = 0;
    __syncthreads();
    int c  = threadIdx.x & 127;
    int ro = threadIdx.x >> 7;
    const float sc = scale[c];
    const float sh = shift[c];
    for (int r = blockIdx.x * 2 + ro; r < n; r += gridDim.x * 2) {
        int g = gid[r];
        float v = (float)z[(size_t)r * 128 + c] * sc + sh;
        atomicAdd(&ls[g * 128 + c], v);
        if (c == 0) atomicAdd(&lc[g], 1);
    }
    __syncthreads();
    for (int i = threadIdx.x; i < NG * 128; i += 256) atomicAdd(&gsum[i], ls[i]);
    if (threadIdx.x < NG) atomicAdd(&gcnt[threadIdx.x], lc[threadIdx.x]);
}

__global__ void k_final(const float* __restrict__ gsum, const int* __restrict__ gcnt,
                        float* __restrict__ out) {
    int i = blockIdx.x * 256 + threadIdx.x;
    if (i < NG * 128) {
        int g = i >> 7;
        out[i] = gsum[i] / fmaxf((float)gcnt[g], 1.0f);
    }
}

// ---------------- host ----------------

extern "C" void kernel_launch(void* const* d_in, const int* in_sizes, int n_in,
                              void* d_out, int out_size, void* d_ws, size_t ws_size,
                              hipStream_t stream) {
    const float* x   = (const float*)d_in[0];
    const int*   src = (const int*)d_in[1];
    const int*   dst = (const int*)d_in[2];
    const int*   gid = (const int*)d_in[3];
    const int n = in_sizes[0] / 128;
    const int E = in_sizes[1];

    auto align = [](size_t o) { return (o + 255) & ~(size_t)255; };
    char* ws = (char*)d_ws;
    size_t off = 0;
    const size_t SZ_H = align((size_t)n * 256 * sizeof(_Float16));
    const size_t SZ_I = align((size_t)n * sizeof(int));
    const int gx = (n + 63) / 64;

    _Float16* h0 = (_Float16*)(ws + off); off += align((size_t)n * 128 * sizeof(_Float16));
    _Float16* P0 = (_Float16*)(ws + off); off += SZ_H;
    _Float16* P1 = (_Float16*)(ws + off); off += SZ_H;
    int*   deg  = (int*)(ws + off);   off += SZ_I;
    int*   incl = (int*)(ws + off);   off += SZ_I;
    int*   rowp = (int*)(ws + off);   off += SZ_I;
    int*   cur  = (int*)(ws + off);   off += SZ_I;
    int*   bsum = (int*)(ws + off);   off += 256 * sizeof(int);
    int*   ss   = (int*)(ws + off);   off += align((size_t)E * sizeof(int));
    float* partial = (float*)(ws + off); off += align((size_t)gx * 2 * 2 * 256 * sizeof(float));
    float* scale   = (float*)(ws + off); off += align(256 * sizeof(float));
    float* shiftb  = (float*)(ws + off); off += align(256 * sizeof(float));
    float* gsum = (float*)(ws + off); off += align(NG * 128 * sizeof(float));
    int*   gcnt = (int*)(ws + off);   off += align(NG * sizeof(int));
    _Float16* wh[6];
    for (int i = 0; i < 6; ++i) { wh[i] = (_Float16*)(ws + off); off += align(65536 * sizeof(_Float16)); }

    const int Ks[3]    = {128, 256, 256};
    const int Mids[3]  = {256, 256, 128};
    const int Mouts[3] = {256, 256, 128};

    // ---- casts ----
    k_cast16<<<(n * 128 / 8 + 255) / 256, 256, 0, stream>>>(x, h0, n * 128 / 8);
    for (int L = 0; L < 3; ++L) {
        const int base = 4 + 7 * L;
        int n1 = Mids[L] * Ks[L];
        int n2 = Mouts[L] * Mids[L];
        k_cast16<<<(n1 / 8 + 255) / 256, 256, 0, stream>>>((const float*)d_in[base + 0], wh[2 * L + 0], n1 / 8);
        k_cast16<<<(n2 / 8 + 255) / 256, 256, 0, stream>>>((const float*)d_in[base + 2], wh[2 * L + 1], n2 / 8);
    }

    // ---- CSR build (dst-keyed) ----
    hipMemsetAsync(deg, 0, (size_t)n * sizeof(int), stream);
    k_deg<<<(E + 255) / 256, 256, 0, stream>>>(dst, deg, E);
    int nb = (n + 1023) / 1024;
    k_scan_a<<<nb, 1024, 0, stream>>>(deg, incl, bsum, n);
    k_scan_b<<<1, 1, 0, stream>>>(bsum, nb);
    k_scan_c<<<(n + 255) / 256, 256, 0, stream>>>(incl, deg, bsum, rowp, n);
    hipMemsetAsync(cur, 0, (size_t)n * sizeof(int), stream);
    k_scatter<<<(E + 255) / 256, 256, 0, stream>>>(src, dst, rowp, cur, ss, E);

    // ---- layers ----
    for (int L = 0; L < 3; ++L) {
        const int base = 4 + 7 * L;
        const float* b1    = (const float*)d_in[base + 1];
        const float* b2    = (const float*)d_in[base + 3];
        const float* eps   = (const float*)d_in[base + 4];
        const float* gamma = (const float*)d_in[base + 5];
        const float* beta  = (const float*)d_in[base + 6];
        const int Mout = Mouts[L];

        if (L == 0) {
            k_agg16<128, false><<<(n + 15) / 16, 256, 0, stream>>>(
                h0, rowp, deg, ss, eps, nullptr, nullptr, P1, n);
            k_mlp<128, 256, 256><<<gx, 512, 0, stream>>>(P1, wh[0], b1, wh[1], b2, P0, partial, n);
        } else if (L == 1) {
            k_agg16<256, true><<<(n + 7) / 8, 256, 0, stream>>>(
                P0, rowp, deg, ss, eps, scale, shiftb, P1, n);
            k_mlp<256, 256, 256><<<gx, 512, 0, stream>>>(P1, wh[2], b1, wh[3], b2, P0, partial, n);
        } else {
            k_agg16<256, true><<<(n + 7) / 8, 256, 0, stream>>>(
                P0, rowp, deg, ss, eps, scale, shiftb, P1, n);
            k_mlp<256, 128, 128><<<gx, 512, 0, stream>>>(P1, wh[4], b1, wh[5], b2, P0, partial, n);
        }

        if (Mout == 256) k_bnred<256><<<64, 256, 0, stream>>>(partial, gamma, beta, scale, shiftb, n, gx * 2);
        else             k_bnred<128><<<32, 256, 0, stream>>>(partial, gamma, beta, scale, shiftb, n, gx * 2);
    }

    // ---- readout (applies layer-2 BN affine) ----
    hipMemsetAsync(gsum, 0, NG * 128 * sizeof(float), stream);
    hipMemsetAsync(gcnt, 0, NG * sizeof(int), stream);
    k_readout_bn<<<256, 256, 0, stream>>>(P0, scale, shiftb, gid, gsum, gcnt, n);
    k_final<<<4, 256, 0, stream>>>(gsum, gcnt, (float*)d_out);
}

// Round 10
// 438.389 us; speedup vs baseline: 1.1962x; 1.1962x over previous
//
#include <hip/hip_runtime.h>

#define NG 8   // graphs

typedef _Float16 half8  __attribute__((ext_vector_type(8)));
typedef float    f32x16 __attribute__((ext_vector_type(16)));

// ---------------- casts ----------------

__global__ __launch_bounds__(256)
void k_cast16(const float* __restrict__ in, _Float16* __restrict__ out, int n8) {
    int i = blockIdx.x * 256 + threadIdx.x;
    if (i < n8) {
        const float4 a = *(const float4*)(in + (size_t)i * 8);
        const float4 b = *(const float4*)(in + (size_t)i * 8 + 4);
        half8 o;
        o[0] = (_Float16)a.x; o[1] = (_Float16)a.y; o[2] = (_Float16)a.z; o[3] = (_Float16)a.w;
        o[4] = (_Float16)b.x; o[5] = (_Float16)b.y; o[6] = (_Float16)b.z; o[7] = (_Float16)b.w;
        *(half8*)(out + (size_t)i * 8) = o;
    }
}

// ---------------- CSR build ----------------

__global__ __launch_bounds__(256)
void k_deg(const int* __restrict__ dst, int* __restrict__ deg, int E) {
    int i = blockIdx.x * 256 + threadIdx.x;
    if (i < E) atomicAdd(&deg[dst[i]], 1);
}

__global__ __launch_bounds__(1024)
void k_scan_a(const int* __restrict__ deg, int* __restrict__ incl,
              int* __restrict__ bsum, int n) {
    __shared__ int s[1024];
    int t = threadIdx.x;
    int base = blockIdx.x * 1024;
    int v = (base + t < n) ? deg[base + t] : 0;
    s[t] = v;
    __syncthreads();
    for (int off = 1; off < 1024; off <<= 1) {
        int x = 0;
        if (t >= off) x = s[t - off];
        __syncthreads();
        if (t >= off) s[t] += x;
        __syncthreads();
    }
    if (base + t < n) incl[base + t] = s[t];
    if (t == 1023) bsum[blockIdx.x] = s[1023];
}

__global__ void k_scan_b(int* bsum, int nb) {
    if (threadIdx.x == 0 && blockIdx.x == 0) {
        int run = 0;
        for (int i = 0; i < nb; ++i) { int v = bsum[i]; bsum[i] = run; run += v; }
    }
}

__global__ __launch_bounds__(256)
void k_scan_c(const int* __restrict__ incl, const int* __restrict__ deg,
              const int* __restrict__ bsum, int* __restrict__ rowp, int n) {
    int i = blockIdx.x * 256 + threadIdx.x;
    if (i < n) rowp[i] = incl[i] - deg[i] + bsum[i >> 10];
}

__global__ __launch_bounds__(256)
void k_scatter(const int* __restrict__ src, const int* __restrict__ dst,
               const int* __restrict__ rowp, int* __restrict__ cur,
               int* __restrict__ ss, int E) {
    int i = blockIdx.x * 256 + threadIdx.x;
    if (i < E) {
        int d = dst[i];
        int pos = rowp[d] + atomicAdd(&cur[d], 1);
        ss[pos] = src[i];
    }
}

// ---------------- aggregation (fp16 rows, fp32 accum), fused BN-apply+ReLU ----------------

template<int K, bool AFFINE>
__global__ __launch_bounds__(256)
void k_agg16(const _Float16* __restrict__ h, const int* __restrict__ rowp,
             const int* __restrict__ deg, const int* __restrict__ ss,
             const float* __restrict__ eps, const float* __restrict__ scp,
             const float* __restrict__ shp, _Float16* __restrict__ z, int n) {
    constexpr int TPN = K / 8;
    constexpr int NPB = 256 / TPN;
    int node = blockIdx.x * NPB + threadIdx.x / TPN;
    int lane = threadIdx.x % TPN;
    if (node >= n) return;
    float e1 = 1.0f + eps[0];
    const int c0 = lane * 8;
    float sc[8], sh[8];
    if (AFFINE) {
#pragma unroll
        for (int e = 0; e < 8; ++e) { sc[e] = scp[c0 + e]; sh[e] = shp[c0 + e]; }
    }
    size_t base = (size_t)node * K + c0;
    half8 v = *(const half8*)(h + base);
    float a[8];
#pragma unroll
    for (int e = 0; e < 8; ++e) {
        float f = (float)v[e];
        if (AFFINE) f = fmaxf(f * sc[e] + sh[e], 0.0f);
        a[e] = f * e1;
    }
    int s  = rowp[node];
    int dn = deg[node];
    int j = 0;
    for (; j + 4 <= dn; j += 4) {
        int u0 = ss[s + j], u1 = ss[s + j + 1], u2 = ss[s + j + 2], u3 = ss[s + j + 3];
        half8 h0 = *(const half8*)(h + (size_t)u0 * K + c0);
        half8 h1 = *(const half8*)(h + (size_t)u1 * K + c0);
        half8 h2 = *(const half8*)(h + (size_t)u2 * K + c0);
        half8 h3 = *(const half8*)(h + (size_t)u3 * K + c0);
#pragma unroll
        for (int e = 0; e < 8; ++e) {
            float f0 = (float)h0[e], f1 = (float)h1[e];
            float f2 = (float)h2[e], f3 = (float)h3[e];
            if (AFFINE) {
                f0 = fmaxf(f0 * sc[e] + sh[e], 0.0f);
                f1 = fmaxf(f1 * sc[e] + sh[e], 0.0f);
                f2 = fmaxf(f2 * sc[e] + sh[e], 0.0f);
                f3 = fmaxf(f3 * sc[e] + sh[e], 0.0f);
            }
            a[e] += (f0 + f1) + (f2 + f3);
        }
    }
    for (; j < dn; ++j) {
        int u = ss[s + j];
        half8 hv = *(const half8*)(h + (size_t)u * K + c0);
#pragma unroll
        for (int e = 0; e < 8; ++e) {
            float f = (float)hv[e];
            if (AFFINE) f = fmaxf(f * sc[e] + sh[e], 0.0f);
            a[e] += f;
        }
    }
    half8 o;
#pragma unroll
    for (int e = 0; e < 8; ++e) o[e] = (_Float16)a[e];
    *(half8*)(z + base) = o;
}

// ---------------- fused MLP v2: W in registers, full-K LDS, 32x32x16 MFMA ----------------
// C = (A@W1^T + b1).relu() @ W2^T + b2, BN partials per block (no atomics).
// Block: 64 rows, 512 threads (8 waves). Wave owns 32 output cols per phase.
// MID==256: 8 col-waves over 64 rows (2 m-frags); MID==128: 2x4 (rows x cols), 1 m-frag.
// LDS: As[64][512B] + Ys[64][512B], XOR swizzle: byteoff ^= (row&31)<<4. Two barriers total.
// 32x32x16 f16 MFMA: A/B frag = 8 halves: row/col = lane&31, k = (lane>>5)*8+j.
// C/D: col = lane&31, row = (reg&3) + 8*(reg>>2) + 4*(lane>>5)   [m74/m101].

template<int K, int MID, int MOUT>
__global__ __launch_bounds__(512)
void k_mlp2(const _Float16* __restrict__ A, const _Float16* __restrict__ W1,
            const float* __restrict__ b1, const _Float16* __restrict__ W2,
            const float* __restrict__ b2, _Float16* __restrict__ C,
            float* __restrict__ partial, int n) {
    constexpr int NK1 = K / 16;       // k-slices phase 1
    constexpr int NK2 = MID / 16;     // k-slices phase 2
    constexpr int NS  = K / 8;        // 16B slots per A row
    constexpr int MF1 = (MID == 256) ? 2 : 1;
    constexpr int MF2 = (MOUT == 256) ? 2 : 1;
    __shared__ char smem[65536];
    char* As = smem;                  // [64][512B] swizzled
    char* Ys = smem + 32768;          // [64][512B] swizzled
    const int tid  = threadIdx.x;
    const int lane = tid & 63;
    const int wid  = tid >> 6;
    const int lo   = lane & 31;
    const int hi   = lane >> 5;
    const int brow = blockIdx.x * 64;

    // ---- W1 fragments in registers (cols colbase1 + lo, all k) ----
    const int wc1 = (MID == 256) ? wid : (wid & 3);
    const int wr1 = (MID == 256) ? 0   : (wid >> 2);
    const int colbase1 = wc1 * 32;
    half8 w1f[NK1];
#pragma unroll
    for (int ks = 0; ks < NK1; ++ks)
        w1f[ks] = *(const half8*)(W1 + (size_t)(colbase1 + lo) * K + ks * 16 + hi * 8);
    const float bb1 = b1[colbase1 + lo];

    // ---- stage A[64][K] -> As (coalesced global, swizzled LDS) ----
    {
        const int r = tid >> 3;
        int ga = brow + r; if (ga > n - 1) ga = n - 1;
        const char* Ab = (const char*)(A + (size_t)ga * K);
#pragma unroll
        for (int i = 0; i < NS / 8; ++i) {
            int l = (tid & 7) + i * 8;
            uint4 v = *(const uint4*)(Ab + l * 16);
            *(uint4*)(As + r * 512 + ((l ^ (r & 31)) << 4)) = v;
        }
    }
    __syncthreads();

    // ---- phase 1: Y = relu(A @ W1^T + b1) ----
    f32x16 acc1[MF1];
#pragma unroll
    for (int mf = 0; mf < MF1; ++mf)
#pragma unroll
        for (int e = 0; e < 16; ++e) acc1[mf][e] = 0.0f;

#pragma unroll
    for (int ks = 0; ks < NK1; ++ks) {
#pragma unroll
        for (int mf = 0; mf < MF1; ++mf) {
            int r = ((wr1 + mf) << 5) + lo;
            half8 af = *(const half8*)(As + r * 512 + ((ks * 32 + hi * 16) ^ ((r & 31) << 4)));
            acc1[mf] = __builtin_amdgcn_mfma_f32_32x32x16_f16(af, w1f[ks], acc1[mf], 0, 0, 0);
        }
    }

    // Ys write (bias + relu, fp16, swizzled)
#pragma unroll
    for (int mf = 0; mf < MF1; ++mf) {
        int rb = ((wr1 + mf) << 5) + (hi << 2);
#pragma unroll
        for (int j = 0; j < 16; ++j) {
            int r = rb + (j & 3) + ((j >> 2) << 3);
            float v = fmaxf(acc1[mf][j] + bb1, 0.0f);
            *(_Float16*)(Ys + r * 512 + (((colbase1 + lo) * 2) ^ ((r & 31) << 4))) = (_Float16)v;
        }
    }

    // ---- W2 fragments (issued before barrier to hide L2 latency) ----
    const int wc2 = (MOUT == 256) ? wid : (wid & 3);
    const int wr2 = (MOUT == 256) ? 0   : (wid >> 2);
    const int colbase2 = wc2 * 32;
    half8 w2f[NK2];
#pragma unroll
    for (int ks = 0; ks < NK2; ++ks)
        w2f[ks] = *(const half8*)(W2 + (size_t)(colbase2 + lo) * MID + ks * 16 + hi * 8);
    const float bb2 = b2[colbase2 + lo];

    __syncthreads();   // Ys visible to all waves

    // ---- phase 2: C = Y @ W2^T + b2 ----
    f32x16 acc2[MF2];
#pragma unroll
    for (int mf = 0; mf < MF2; ++mf)
#pragma unroll
        for (int e = 0; e < 16; ++e) acc2[mf][e] = 0.0f;

#pragma unroll
    for (int ks = 0; ks < NK2; ++ks) {
#pragma unroll
        for (int mf = 0; mf < MF2; ++mf) {
            int r = ((wr2 + mf) << 5) + lo;
            half8 af = *(const half8*)(Ys + r * 512 + ((ks * 32 + hi * 16) ^ ((r & 31) << 4)));
            acc2[mf] = __builtin_amdgcn_mfma_f32_32x32x16_f16(af, w2f[ks], acc2[mf], 0, 0, 0);
        }
    }

    // ---- epilogue: per-wave LDS transpose -> coalesced stores + BN partials ----
    // tb in As region: safe, all waves are past phase 1 (post-barrier), per-wave private.
    char* tb = smem + wid * 2304;     // [32][72B] fp16
    const int g  = lane & 3;          // 8-col group
    const int rl = lane >> 2;         // 0..15
    float s[8], q[8];
#pragma unroll
    for (int e = 0; e < 8; ++e) { s[e] = 0.f; q[e] = 0.f; }

#pragma unroll
    for (int mf = 0; mf < MF2; ++mf) {
#pragma unroll
        for (int j = 0; j < 16; ++j) {
            int tr = (j & 3) + ((j >> 2) << 3) + (hi << 2);
            *(_Float16*)(tb + tr * 72 + lo * 2) = (_Float16)(acc2[mf][j] + bb2);
        }
        // per-wave DS ordering: reads below observe writes above (in-order within wave)
#pragma unroll
        for (int it = 0; it < 2; ++it) {
            int lr = it * 16 + rl;
            int grow = brow + ((wr2 + mf) << 5) + lr;
            half8 v = *(const half8*)(tb + lr * 72 + g * 16);
            if (grow < n) {
                *(half8*)(C + (size_t)grow * MOUT + colbase2 + g * 8) = v;
#pragma unroll
                for (int e = 0; e < 8; ++e) { float f = (float)v[e]; s[e] += f; q[e] += f * f; }
            }
        }
    }
#pragma unroll
    for (int e = 0; e < 8; ++e) {
        for (int mk = 4; mk < 64; mk <<= 1) {
            s[e] += __shfl_xor(s[e], mk, 64);
            q[e] += __shfl_xor(q[e], mk, 64);
        }
    }
    if (lane < 4) {
        float* p = partial + ((size_t)blockIdx.x * 2 + wr2) * (2 * MOUT);
#pragma unroll
        for (int e = 0; e < 8; ++e) {
            p[colbase2 + lane * 8 + e]        = s[e];
            p[MOUT + colbase2 + lane * 8 + e] = q[e];
        }
    }
}

// ---------------- BN reduce: strided partial rows -> scale/shift ----------------
// grid = M/4 blocks x 256 threads (1 wave per column). row b uses partial[(b*step)*2M].

template<int M>
__global__ __launch_bounds__(256)
void k_bnred(const float* __restrict__ partial, const float* __restrict__ gamma,
             const float* __restrict__ beta, float* __restrict__ scale,
             float* __restrict__ shift, int n, int count, int step) {
    const int w = threadIdx.x >> 6, lane = threadIdx.x & 63;
    const int c = blockIdx.x * 4 + w;
    float s = 0.f, q = 0.f;
    for (int b = lane; b < count; b += 64) {
        const float* p = partial + (size_t)(b * step) * (2 * M);
        s += p[c];
        q += p[M + c];
    }
#pragma unroll
    for (int mk = 1; mk < 64; mk <<= 1) {
        s += __shfl_xor(s, mk, 64);
        q += __shfl_xor(q, mk, 64);
    }
    if (lane == 0) {
        float invN = 1.0f / (float)n;
        float mean = s * invN;
        float var  = q * invN - mean * mean;
        float sc   = rsqrtf(var + 1e-5f) * gamma[c];
        scale[c] = sc;
        shift[c] = beta[c] - mean * sc;
    }
}

// ---------------- graph readout (fused final BN affine) ----------------

__global__ __launch_bounds__(256)
void k_readout_bn(const _Float16* __restrict__ z, const float* __restrict__ scale,
                  const float* __restrict__ shift, const int* __restrict__ gid,
                  float* __restrict__ gsum, int* __restrict__ gcnt, int n) {
    __shared__ float ls[NG * 128];
    __shared__ int   lc[NG];
    for (int i = threadIdx.x; i < NG * 128; i += 256) ls[i] = 0.0f;
    if (threadIdx.x < NG) lc[threadIdx.x] = 0;
    __syncthreads();
    int c  = threadIdx.x & 127;
    int ro = threadIdx.x >> 7;
    const float sc = scale[c];
    const float sh = shift[c];
    for (int r = blockIdx.x * 2 + ro; r < n; r += gridDim.x * 2) {
        int g = gid[r];
        float v = (float)z[(size_t)r * 128 + c] * sc + sh;
        atomicAdd(&ls[g * 128 + c], v);
        if (c == 0) atomicAdd(&lc[g], 1);
    }
    __syncthreads();
    for (int i = threadIdx.x; i < NG * 128; i += 256) atomicAdd(&gsum[i], ls[i]);
    if (threadIdx.x < NG) atomicAdd(&gcnt[threadIdx.x], lc[threadIdx.x]);
}

__global__ void k_final(const float* __restrict__ gsum, const int* __restrict__ gcnt,
                        float* __restrict__ out) {
    int i = blockIdx.x * 256 + threadIdx.x;
    if (i < NG * 128) {
        int g = i >> 7;
        out[i] = gsum[i] / fmaxf((float)gcnt[g], 1.0f);
    }
}

// ---------------- host ----------------

extern "C" void kernel_launch(void* const* d_in, const int* in_sizes, int n_in,
                              void* d_out, int out_size, void* d_ws, size_t ws_size,
                              hipStream_t stream) {
    const float* x   = (const float*)d_in[0];
    const int*   src = (const int*)d_in[1];
    const int*   dst = (const int*)d_in[2];
    const int*   gid = (const int*)d_in[3];
    const int n = in_sizes[0] / 128;
    const int E = in_sizes[1];

    auto align = [](size_t o) { return (o + 255) & ~(size_t)255; };
    char* ws = (char*)d_ws;
    size_t off = 0;
    const size_t SZ_H = align((size_t)n * 256 * sizeof(_Float16));
    const size_t SZ_I = align((size_t)n * sizeof(int));
    const int gx = (n + 63) / 64;

    _Float16* h0 = (_Float16*)(ws + off); off += align((size_t)n * 128 * sizeof(_Float16));
    _Float16* P0 = (_Float16*)(ws + off); off += SZ_H;
    _Float16* P1 = (_Float16*)(ws + off); off += SZ_H;
    int*   deg  = (int*)(ws + off);   off += SZ_I;
    int*   incl = (int*)(ws + off);   off += SZ_I;
    int*   rowp = (int*)(ws + off);   off += SZ_I;
    int*   cur  = (int*)(ws + off);   off += SZ_I;
    int*   bsum = (int*)(ws + off);   off += 256 * sizeof(int);
    int*   ss   = (int*)(ws + off);   off += align((size_t)E * sizeof(int));
    float* partial = (float*)(ws + off); off += align((size_t)gx * 2 * 2 * 256 * sizeof(float));
    float* scale   = (float*)(ws + off); off += align(256 * sizeof(float));
    float* shiftb  = (float*)(ws + off); off += align(256 * sizeof(float));
    float* gsum = (float*)(ws + off); off += align(NG * 128 * sizeof(float));
    int*   gcnt = (int*)(ws + off);   off += align(NG * sizeof(int));
    _Float16* wh[6];
    for (int i = 0; i < 6; ++i) { wh[i] = (_Float16*)(ws + off); off += align(65536 * sizeof(_Float16)); }

    const int Ks[3]    = {128, 256, 256};
    const int Mids[3]  = {256, 256, 128};
    const int Mouts[3] = {256, 256, 128};

    // ---- casts ----
    k_cast16<<<(n * 128 / 8 + 255) / 256, 256, 0, stream>>>(x, h0, n * 128 / 8);
    for (int L = 0; L < 3; ++L) {
        const int base = 4 + 7 * L;
        int n1 = Mids[L] * Ks[L];
        int n2 = Mouts[L] * Mids[L];
        k_cast16<<<(n1 / 8 + 255) / 256, 256, 0, stream>>>((const float*)d_in[base + 0], wh[2 * L + 0], n1 / 8);
        k_cast16<<<(n2 / 8 + 255) / 256, 256, 0, stream>>>((const float*)d_in[base + 2], wh[2 * L + 1], n2 / 8);
    }

    // ---- CSR build (dst-keyed) ----
    hipMemsetAsync(deg, 0, (size_t)n * sizeof(int), stream);
    k_deg<<<(E + 255) / 256, 256, 0, stream>>>(dst, deg, E);
    int nb = (n + 1023) / 1024;
    k_scan_a<<<nb, 1024, 0, stream>>>(deg, incl, bsum, n);
    k_scan_b<<<1, 1, 0, stream>>>(bsum, nb);
    k_scan_c<<<(n + 255) / 256, 256, 0, stream>>>(incl, deg, bsum, rowp, n);
    hipMemsetAsync(cur, 0, (size_t)n * sizeof(int), stream);
    k_scatter<<<(E + 255) / 256, 256, 0, stream>>>(src, dst, rowp, cur, ss, E);

    // ---- layers ----
    for (int L = 0; L < 3; ++L) {
        const int base = 4 + 7 * L;
        const float* b1    = (const float*)d_in[base + 1];
        const float* b2    = (const float*)d_in[base + 3];
        const float* eps   = (const float*)d_in[base + 4];
        const float* gamma = (const float*)d_in[base + 5];
        const float* beta  = (const float*)d_in[base + 6];

        if (L == 0) {
            k_agg16<128, false><<<(n + 15) / 16, 256, 0, stream>>>(
                h0, rowp, deg, ss, eps, nullptr, nullptr, P1, n);
            k_mlp2<128, 256, 256><<<gx, 512, 0, stream>>>(P1, wh[0], b1, wh[1], b2, P0, partial, n);
            k_bnred<256><<<64, 256, 0, stream>>>(partial, gamma, beta, scale, shiftb, n, gx, 2);
        } else if (L == 1) {
            k_agg16<256, true><<<(n + 7) / 8, 256, 0, stream>>>(
                P0, rowp, deg, ss, eps, scale, shiftb, P1, n);
            k_mlp2<256, 256, 256><<<gx, 512, 0, stream>>>(P1, wh[2], b1, wh[3], b2, P0, partial, n);
            k_bnred<256><<<64, 256, 0, stream>>>(partial, gamma, beta, scale, shiftb, n, gx, 2);
        } else {
            k_agg16<256, true><<<(n + 7) / 8, 256, 0, stream>>>(
                P0, rowp, deg, ss, eps, scale, shiftb, P1, n);
            k_mlp2<256, 128, 128><<<gx, 512, 0, stream>>>(P1, wh[4], b1, wh[5], b2, P0, partial, n);
            k_bnred<128><<<32, 256, 0, stream>>>(partial, gamma, beta, scale, shiftb, n, 2 * gx, 1);
        }
    }

    // ---- readout (applies layer-2 BN affine) ----
    hipMemsetAsync(gsum, 0, NG * 128 * sizeof(float), stream);
    hipMemsetAsync(gcnt, 0, NG * sizeof(int), stream);
    k_readout_bn<<<256, 256, 0, stream>>>(P0, scale, shiftb, gid, gsum, gcnt, n);
    k_final<<<4, 256, 0, stream>>>(gsum, gcnt, (float*)d_out);
}

// Round 11
// 411.487 us; speedup vs baseline: 1.2744x; 1.0654x over previous
//
#include <hip/hip_runtime.h>

#define NG 8   // graphs

typedef _Float16 half8  __attribute__((ext_vector_type(8)));
typedef float    f32x16 __attribute__((ext_vector_type(16)));

// ---------------- casts ----------------

__global__ __launch_bounds__(256)
void k_cast16(const float* __restrict__ in, _Float16* __restrict__ out, int n8) {
    int i = blockIdx.x * 256 + threadIdx.x;
    if (i < n8) {
        const float4 a = *(const float4*)(in + (size_t)i * 8);
        const float4 b = *(const float4*)(in + (size_t)i * 8 + 4);
        half8 o;
        o[0] = (_Float16)a.x; o[1] = (_Float16)a.y; o[2] = (_Float16)a.z; o[3] = (_Float16)a.w;
        o[4] = (_Float16)b.x; o[5] = (_Float16)b.y; o[6] = (_Float16)b.z; o[7] = (_Float16)b.w;
        *(half8*)(out + (size_t)i * 8) = o;
    }
}

// all 6 weight matrices in one launch. segments (8-elem units):
// w1_0 4096 | w2_0 8192 | w1_1 8192 | w2_1 8192 | w1_2 4096 | w2_2 2048  (total 34816)
__global__ __launch_bounds__(256)
void k_castw(const float* __restrict__ w0, const float* __restrict__ w1,
             const float* __restrict__ w2, const float* __restrict__ w3,
             const float* __restrict__ w4, const float* __restrict__ w5,
             _Float16* __restrict__ o0, _Float16* __restrict__ o1,
             _Float16* __restrict__ o2, _Float16* __restrict__ o3,
             _Float16* __restrict__ o4, _Float16* __restrict__ o5) {
    int i = blockIdx.x * 256 + threadIdx.x;
    const float* in; _Float16* out; int off;
    if      (i <  4096) { in = w0; out = o0; off = 0;     }
    else if (i < 12288) { in = w1; out = o1; off = 4096;  }
    else if (i < 20480) { in = w2; out = o2; off = 12288; }
    else if (i < 28672) { in = w3; out = o3; off = 20480; }
    else if (i < 32768) { in = w4; out = o4; off = 28672; }
    else if (i < 34816) { in = w5; out = o5; off = 32768; }
    else return;
    int j = i - off;
    const float4 a = *(const float4*)(in + (size_t)j * 8);
    const float4 b = *(const float4*)(in + (size_t)j * 8 + 4);
    half8 o;
    o[0] = (_Float16)a.x; o[1] = (_Float16)a.y; o[2] = (_Float16)a.z; o[3] = (_Float16)a.w;
    o[4] = (_Float16)b.x; o[5] = (_Float16)b.y; o[6] = (_Float16)b.z; o[7] = (_Float16)b.w;
    *(half8*)(out + (size_t)j * 8) = o;
}

// ---------------- CSR build ----------------

__global__ __launch_bounds__(256)
void k_deg(const int* __restrict__ dst, int* __restrict__ deg, int E) {
    int i = blockIdx.x * 256 + threadIdx.x;
    if (i < E) atomicAdd(&deg[dst[i]], 1);
}

__global__ __launch_bounds__(1024)
void k_scan_a(const int* __restrict__ deg, int* __restrict__ incl,
              int* __restrict__ bsum, int n) {
    __shared__ int s[1024];
    int t = threadIdx.x;
    int base = blockIdx.x * 1024;
    int v = (base + t < n) ? deg[base + t] : 0;
    s[t] = v;
    __syncthreads();
    for (int off = 1; off < 1024; off <<= 1) {
        int x = 0;
        if (t >= off) x = s[t - off];
        __syncthreads();
        if (t >= off) s[t] += x;
        __syncthreads();
    }
    if (base + t < n) incl[base + t] = s[t];
    if (t == 1023) bsum[blockIdx.x] = s[1023];
}

__global__ void k_scan_b(int* bsum, int nb) {
    if (threadIdx.x == 0 && blockIdx.x == 0) {
        int run = 0;
        for (int i = 0; i < nb; ++i) { int v = bsum[i]; bsum[i] = run; run += v; }
    }
}

__global__ __launch_bounds__(256)
void k_scan_c(const int* __restrict__ incl, const int* __restrict__ deg,
              const int* __restrict__ bsum, int* __restrict__ rowp, int n) {
    int i = blockIdx.x * 256 + threadIdx.x;
    if (i < n) rowp[i] = incl[i] - deg[i] + bsum[i >> 10];
}

__global__ __launch_bounds__(256)
void k_scatter(const int* __restrict__ src, const int* __restrict__ dst,
               const int* __restrict__ rowp, int* __restrict__ cur,
               int* __restrict__ ss, int E) {
    int i = blockIdx.x * 256 + threadIdx.x;
    if (i < E) {
        int d = dst[i];
        int pos = rowp[d] + atomicAdd(&cur[d], 1);
        ss[pos] = src[i];
    }
}

// ---------------- aggregation (fp16 rows, fp32 accum), fused BN-apply+ReLU ----------------

template<int K, bool AFFINE>
__global__ __launch_bounds__(256)
void k_agg16(const _Float16* __restrict__ h, const int* __restrict__ rowp,
             const int* __restrict__ deg, const int* __restrict__ ss,
             const float* __restrict__ eps, const float* __restrict__ scp,
             const float* __restrict__ shp, _Float16* __restrict__ z, int n) {
    constexpr int TPN = K / 8;
    constexpr int NPB = 256 / TPN;
    int node = blockIdx.x * NPB + threadIdx.x / TPN;
    int lane = threadIdx.x % TPN;
    if (node >= n) return;
    float e1 = 1.0f + eps[0];
    const int c0 = lane * 8;
    float sc[8], sh[8];
    if (AFFINE) {
#pragma unroll
        for (int e = 0; e < 8; ++e) { sc[e] = scp[c0 + e]; sh[e] = shp[c0 + e]; }
    }
    size_t base = (size_t)node * K + c0;
    half8 v = *(const half8*)(h + base);
    float a[8];
#pragma unroll
    for (int e = 0; e < 8; ++e) {
        float f = (float)v[e];
        if (AFFINE) f = fmaxf(f * sc[e] + sh[e], 0.0f);
        a[e] = f * e1;
    }
    int s  = rowp[node];
    int dn = deg[node];
    int j = 0;
    for (; j + 4 <= dn; j += 4) {
        int u0 = ss[s + j], u1 = ss[s + j + 1], u2 = ss[s + j + 2], u3 = ss[s + j + 3];
        half8 h0 = *(const half8*)(h + (size_t)u0 * K + c0);
        half8 h1 = *(const half8*)(h + (size_t)u1 * K + c0);
        half8 h2 = *(const half8*)(h + (size_t)u2 * K + c0);
        half8 h3 = *(const half8*)(h + (size_t)u3 * K + c0);
#pragma unroll
        for (int e = 0; e < 8; ++e) {
            float f0 = (float)h0[e], f1 = (float)h1[e];
            float f2 = (float)h2[e], f3 = (float)h3[e];
            if (AFFINE) {
                f0 = fmaxf(f0 * sc[e] + sh[e], 0.0f);
                f1 = fmaxf(f1 * sc[e] + sh[e], 0.0f);
                f2 = fmaxf(f2 * sc[e] + sh[e], 0.0f);
                f3 = fmaxf(f3 * sc[e] + sh[e], 0.0f);
            }
            a[e] += (f0 + f1) + (f2 + f3);
        }
    }
    for (; j < dn; ++j) {
        int u = ss[s + j];
        half8 hv = *(const half8*)(h + (size_t)u * K + c0);
#pragma unroll
        for (int e = 0; e < 8; ++e) {
            float f = (float)hv[e];
            if (AFFINE) f = fmaxf(f * sc[e] + sh[e], 0.0f);
            a[e] += f;
        }
    }
    half8 o;
#pragma unroll
    for (int e = 0; e < 8; ++e) o[e] = (_Float16)a[e];
    *(half8*)(z + base) = o;
}

// ---------------- fused MLP v3: PERSISTENT blocks, W in registers ----------------
// C = (A@W1^T + b1).relu() @ W2^T + b2, BN partials per block (no atomics).
// grid = NBLK blocks x 512 thr; each block loops over 64-row tiles (tile += gridDim.x).
// W1/W2 fragments + biases loaded ONCE per block. A tile prefetched into regs
// during previous tile's MFMA phases. 2 barriers per tile. Dedicated LDS transpose buf.
// 32x32x16 f16 MFMA; A/B frag: row/col=lane&31, k=(lane>>5)*8+j.
// C/D: col=lane&31, row=(reg&3)+8*(reg>>2)+4*(lane>>5)  [m74/m101].

template<int K, int MID, int MOUT>
__global__ __launch_bounds__(512)
void k_mlp3(const _Float16* __restrict__ A, const _Float16* __restrict__ W1,
            const float* __restrict__ b1, const _Float16* __restrict__ W2,
            const float* __restrict__ b2, _Float16* __restrict__ C,
            float* __restrict__ partial, int n, int ntiles) {
    constexpr int NK1 = K / 16;
    constexpr int NK2 = MID / 16;
    constexpr int MF1 = (MID == 256) ? 2 : 1;
    constexpr int MF2 = (MOUT == 256) ? 2 : 1;
    constexpr int NLD = K / 64;          // uint4 A-loads per thread (256->4, 128->2)
    __shared__ char As[64 * 512];        // swizzled: 16B slot l -> l ^ (row&31)
    __shared__ char Ys[64 * 512];
    __shared__ char tbs[8 * 2304];       // per-wave transpose buffers
    const int tid  = threadIdx.x;
    const int lane = tid & 63;
    const int wid  = tid >> 6;
    const int lo   = lane & 31;
    const int hi   = lane >> 5;

    const int wc1 = (MID == 256) ? wid : (wid & 3);
    const int wr1 = (MID == 256) ? 0   : (wid >> 2);
    const int colbase1 = wc1 * 32;
    const int wc2 = (MOUT == 256) ? wid : (wid & 3);
    const int wr2 = (MOUT == 256) ? 0   : (wid >> 2);
    const int colbase2 = wc2 * 32;

    // ---- W fragments + biases, once per block ----
    half8 w1f[NK1], w2f[NK2];
#pragma unroll
    for (int ks = 0; ks < NK1; ++ks)
        w1f[ks] = *(const half8*)(W1 + (size_t)(colbase1 + lo) * K + ks * 16 + hi * 8);
#pragma unroll
    for (int ks = 0; ks < NK2; ++ks)
        w2f[ks] = *(const half8*)(W2 + (size_t)(colbase2 + lo) * MID + ks * 16 + hi * 8);
    const float bb1 = b1[colbase1 + lo];
    const float bb2 = b2[colbase2 + lo];

    const int sr = tid >> 3;         // staging row 0..63
    const int sl = tid & 7;          // staging 16B slot base
    const int g  = lane & 3;         // epilogue col group
    const int rl = lane >> 2;        // epilogue row lane
    char* tb = tbs + wid * 2304;     // [32][72B]

    float s[8], q[8];
#pragma unroll
    for (int e = 0; e < 8; ++e) { s[e] = 0.f; q[e] = 0.f; }

    int tile = blockIdx.x;
    uint4 ar[NLD];
    if (tile < ntiles) {
        int ga = tile * 64 + sr; if (ga > n - 1) ga = n - 1;
        const char* Ab = (const char*)(A + (size_t)ga * K);
#pragma unroll
        for (int i = 0; i < NLD; ++i) ar[i] = *(const uint4*)(Ab + (sl + i * 8) * 16);
    }

    for (; tile < ntiles; tile += gridDim.x) {
        const int brow = tile * 64;

        // (1) As <- ar   (prev p1 readers done: barrier beta of prev iter)
#pragma unroll
        for (int i = 0; i < NLD; ++i)
            *(uint4*)(As + sr * 512 + (((sl + i * 8) ^ (sr & 31)) << 4)) = ar[i];
        // (2) prefetch next tile's A into regs (lands during MFMA phases)
        int nt = tile + gridDim.x;
        if (nt < ntiles) {
            int ga = nt * 64 + sr; if (ga > n - 1) ga = n - 1;
            const char* Ab = (const char*)(A + (size_t)ga * K);
#pragma unroll
            for (int i = 0; i < NLD; ++i) ar[i] = *(const uint4*)(Ab + (sl + i * 8) * 16);
        }
        __syncthreads();   // alpha: As ready; Ys(prev) fully consumed by all waves

        // ---- phase 1: Y = relu(A @ W1^T + b1) ----
        f32x16 acc1[MF1];
#pragma unroll
        for (int mf = 0; mf < MF1; ++mf)
#pragma unroll
            for (int e = 0; e < 16; ++e) acc1[mf][e] = 0.0f;
#pragma unroll
        for (int ks = 0; ks < NK1; ++ks) {
#pragma unroll
            for (int mf = 0; mf < MF1; ++mf) {
                int r = ((wr1 + mf) << 5) + lo;
                half8 af = *(const half8*)(As + r * 512 + ((ks * 32 + hi * 16) ^ ((r & 31) << 4)));
                acc1[mf] = __builtin_amdgcn_mfma_f32_32x32x16_f16(af, w1f[ks], acc1[mf], 0, 0, 0);
            }
        }
#pragma unroll
        for (int mf = 0; mf < MF1; ++mf) {
            int rb = ((wr1 + mf) << 5) + (hi << 2);
#pragma unroll
            for (int j = 0; j < 16; ++j) {
                int r = rb + (j & 3) + ((j >> 2) << 3);
                float v = fmaxf(acc1[mf][j] + bb1, 0.0f);
                *(_Float16*)(Ys + r * 512 + (((colbase1 + lo) * 2) ^ ((r & 31) << 4))) = (_Float16)v;
            }
        }
        __syncthreads();   // beta: Ys ready; As(this tile) fully consumed

        // ---- phase 2: C = Y @ W2^T + b2 ----
        f32x16 acc2[MF2];
#pragma unroll
        for (int mf = 0; mf < MF2; ++mf)
#pragma unroll
            for (int e = 0; e < 16; ++e) acc2[mf][e] = 0.0f;
#pragma unroll
        for (int ks = 0; ks < NK2; ++ks) {
#pragma unroll
            for (int mf = 0; mf < MF2; ++mf) {
                int r = ((wr2 + mf) << 5) + lo;
                half8 af = *(const half8*)(Ys + r * 512 + ((ks * 32 + hi * 16) ^ ((r & 31) << 4)));
                acc2[mf] = __builtin_amdgcn_mfma_f32_32x32x16_f16(af, w2f[ks], acc2[mf], 0, 0, 0);
            }
        }

        // ---- epilogue: per-wave LDS transpose -> coalesced stores + BN accum ----
#pragma unroll
        for (int mf = 0; mf < MF2; ++mf) {
#pragma unroll
            for (int j = 0; j < 16; ++j) {
                int tr = (j & 3) + ((j >> 2) << 3) + (hi << 2);
                *(_Float16*)(tb + tr * 72 + lo * 2) = (_Float16)(acc2[mf][j] + bb2);
            }
            // per-wave DS ops execute in order: reads below see writes above
#pragma unroll
            for (int it = 0; it < 2; ++it) {
                int lr = it * 16 + rl;
                int grow = brow + ((wr2 + mf) << 5) + lr;
                half8 v = *(const half8*)(tb + lr * 72 + g * 16);
                if (grow < n) {
                    *(half8*)(C + (size_t)grow * MOUT + colbase2 + g * 8) = v;
#pragma unroll
                    for (int e = 0; e < 8; ++e) { float f = (float)v[e]; s[e] += f; q[e] += f * f; }
                }
            }
        }
    }

    // ---- BN partials: one row per (block, row-group), written once ----
#pragma unroll
    for (int e = 0; e < 8; ++e) {
        for (int mk = 4; mk < 64; mk <<= 1) {
            s[e] += __shfl_xor(s[e], mk, 64);
            q[e] += __shfl_xor(q[e], mk, 64);
        }
    }
    if (lane < 4) {
        float* p = partial + ((size_t)blockIdx.x * 2 + wr2) * (2 * MOUT);
#pragma unroll
        for (int e = 0; e < 8; ++e) {
            p[colbase2 + lane * 8 + e]        = s[e];
            p[MOUT + colbase2 + lane * 8 + e] = q[e];
        }
    }
}

// ---------------- BN reduce: strided partial rows -> scale/shift ----------------

template<int M>
__global__ __launch_bounds__(256)
void k_bnred(const float* __restrict__ partial, const float* __restrict__ gamma,
             const float* __restrict__ beta, float* __restrict__ scale,
             float* __restrict__ shift, int n, int count, int step) {
    const int w = threadIdx.x >> 6, lane = threadIdx.x & 63;
    const int c = blockIdx.x * 4 + w;
    float s = 0.f, q = 0.f;
    for (int b = lane; b < count; b += 64) {
        const float* p = partial + (size_t)(b * step) * (2 * M);
        s += p[c];
        q += p[M + c];
    }
#pragma unroll
    for (int mk = 1; mk < 64; mk <<= 1) {
        s += __shfl_xor(s, mk, 64);
        q += __shfl_xor(q, mk, 64);
    }
    if (lane == 0) {
        float invN = 1.0f / (float)n;
        float mean = s * invN;
        float var  = q * invN - mean * mean;
        float sc   = rsqrtf(var + 1e-5f) * gamma[c];
        scale[c] = sc;
        shift[c] = beta[c] - mean * sc;
    }
}

// ---------------- graph readout (fused final BN affine) ----------------

__global__ __launch_bounds__(256)
void k_readout_bn(const _Float16* __restrict__ z, const float* __restrict__ scale,
                  const float* __restrict__ shift, const int* __restrict__ gid,
                  float* __restrict__ gsum, int* __restrict__ gcnt, int n) {
    __shared__ float ls[NG * 128];
    __shared__ int   lc[NG];
    for (int i = threadIdx.x; i < NG * 128; i += 256) ls[i] = 0.0f;
    if (threadIdx.x < NG) lc[threadIdx.x] = 0;
    __syncthreads();
    int c  = threadIdx.x & 127;
    int ro = threadIdx.x >> 7;
    const float sc = scale[c];
    const float sh = shift[c];
    for (int r = blockIdx.x * 2 + ro; r < n; r += gridDim.x * 2) {
        int g = gid[r];
        float v = (float)z[(size_t)r * 128 + c] * sc + sh;
        atomicAdd(&ls[g * 128 + c], v);
        if (c == 0) atomicAdd(&lc[g], 1);
    }
    __syncthreads();
    for (int i = threadIdx.x; i < NG * 128; i += 256) atomicAdd(&gsum[i], ls[i]);
    if (threadIdx.x < NG) atomicAdd(&gcnt[threadIdx.x], lc[threadIdx.x]);
}

__global__ void k_final(const float* __restrict__ gsum, const int* __restrict__ gcnt,
                        float* __restrict__ out) {
    int i = blockIdx.x * 256 + threadIdx.x;
    if (i < NG * 128) {
        int g = i >> 7;
        out[i] = gsum[i] / fmaxf((float)gcnt[g], 1.0f);
    }
}

// ---------------- host ----------------

extern "C" void kernel_launch(void* const* d_in, const int* in_sizes, int n_in,
                              void* d_out, int out_size, void* d_ws, size_t ws_size,
                              hipStream_t stream) {
    const float* x   = (const float*)d_in[0];
    const int*   src = (const int*)d_in[1];
    const int*   dst = (const int*)d_in[2];
    const int*   gid = (const int*)d_in[3];
    const int n = in_sizes[0] / 128;
    const int E = in_sizes[1];

    auto align = [](size_t o) { return (o + 255) & ~(size_t)255; };
    char* ws = (char*)d_ws;
    size_t off = 0;
    const size_t SZ_H = align((size_t)n * 256 * sizeof(_Float16));
    const size_t SZ_I = align((size_t)n * sizeof(int));
    const int gx = (n + 63) / 64;
    const int NBLK = 256;

    _Float16* h0 = (_Float16*)(ws + off); off += align((size_t)n * 128 * sizeof(_Float16));
    _Float16* P0 = (_Float16*)(ws + off); off += SZ_H;
    _Float16* P1 = (_Float16*)(ws + off); off += SZ_H;
    int*   deg  = (int*)(ws + off);   off += SZ_I;
    int*   incl = (int*)(ws + off);   off += SZ_I;
    int*   rowp = (int*)(ws + off);   off += SZ_I;
    int*   cur  = (int*)(ws + off);   off += SZ_I;
    int*   bsum = (int*)(ws + off);   off += 256 * sizeof(int);
    int*   ss   = (int*)(ws + off);   off += align((size_t)E * sizeof(int));
    float* partial = (float*)(ws + off); off += align((size_t)(2 * NBLK) * 2 * 256 * sizeof(float));
    float* scale   = (float*)(ws + off); off += align(256 * sizeof(float));
    float* shiftb  = (float*)(ws + off); off += align(256 * sizeof(float));
    float* gsum = (float*)(ws + off); off += align(NG * 128 * sizeof(float));
    int*   gcnt = (int*)(ws + off);   off += align(NG * sizeof(int));
    _Float16* wh[6];
    for (int i = 0; i < 6; ++i) { wh[i] = (_Float16*)(ws + off); off += align(65536 * sizeof(_Float16)); }

    // ---- casts ----
    k_cast16<<<(n * 128 / 8 + 255) / 256, 256, 0, stream>>>(x, h0, n * 128 / 8);
    k_castw<<<136, 256, 0, stream>>>(
        (const float*)d_in[4], (const float*)d_in[6],
        (const float*)d_in[11], (const float*)d_in[13],
        (const float*)d_in[18], (const float*)d_in[20],
        wh[0], wh[1], wh[2], wh[3], wh[4], wh[5]);

    // ---- CSR build (dst-keyed) ----
    hipMemsetAsync(deg, 0, (size_t)n * sizeof(int), stream);
    k_deg<<<(E + 255) / 256, 256, 0, stream>>>(dst, deg, E);
    int nb = (n + 1023) / 1024;
    k_scan_a<<<nb, 1024, 0, stream>>>(deg, incl, bsum, n);
    k_scan_b<<<1, 1, 0, stream>>>(bsum, nb);
    k_scan_c<<<(n + 255) / 256, 256, 0, stream>>>(incl, deg, bsum, rowp, n);
    hipMemsetAsync(cur, 0, (size_t)n * sizeof(int), stream);
    k_scatter<<<(E + 255) / 256, 256, 0, stream>>>(src, dst, rowp, cur, ss, E);

    // ---- layers ----
    for (int L = 0; L < 3; ++L) {
        const int base = 4 + 7 * L;
        const float* b1    = (const float*)d_in[base + 1];
        const float* b2    = (const float*)d_in[base + 3];
        const float* eps   = (const float*)d_in[base + 4];
        const float* gamma = (const float*)d_in[base + 5];
        const float* beta  = (const float*)d_in[base + 6];

        if (L == 0) {
            k_agg16<128, false><<<(n + 15) / 16, 256, 0, stream>>>(
                h0, rowp, deg, ss, eps, nullptr, nullptr, P1, n);
            k_mlp3<128, 256, 256><<<NBLK, 512, 0, stream>>>(P1, wh[0], b1, wh[1], b2, P0, partial, n, gx);
            k_bnred<256><<<64, 256, 0, stream>>>(partial, gamma, beta, scale, shiftb, n, NBLK, 2);
        } else if (L == 1) {
            k_agg16<256, true><<<(n + 7) / 8, 256, 0, stream>>>(
                P0, rowp, deg, ss, eps, scale, shiftb, P1, n);
            k_mlp3<256, 256, 256><<<NBLK, 512, 0, stream>>>(P1, wh[2], b1, wh[3], b2, P0, partial, n, gx);
            k_bnred<256><<<64, 256, 0, stream>>>(partial, gamma, beta, scale, shiftb, n, NBLK, 2);
        } else {
            k_agg16<256, true><<<(n + 7) / 8, 256, 0, stream>>>(
                P0, rowp, deg, ss, eps, scale, shiftb, P1, n);
            k_mlp3<256, 128, 128><<<NBLK, 512, 0, stream>>>(P1, wh[4], b1, wh[5], b2, P0, partial, n, gx);
            k_bnred<128><<<32, 256, 0, stream>>>(partial, gamma, beta, scale, shiftb, n, 2 * NBLK, 1);
        }
    }

    // ---- readout (applies layer-2 BN affine) ----
    hipMemsetAsync(gsum, 0, NG * 128 * sizeof(float), stream);
    hipMemsetAsync(gcnt, 0, NG * sizeof(int), stream);
    k_readout_bn<<<256, 256, 0, stream>>>(P0, scale, shiftb, gid, gsum, gcnt, n);
    k_final<<<4, 256, 0, stream>>>(gsum, gcnt, (float*)d_out);
}